// Round 2
// baseline (5154.260 us; speedup 1.0000x reference)
//
#include <hip/hip_runtime.h>
#include <math.h>

#define BATCH   4
#define SEQ     2048
#define DMODEL  768
#define DSTATE  16
#define DCONV   4
#define HEADDIM 64
#define DINNER  1536
#define NHEADS  24
#define CONVDIM 1568
#define DINPROJ 3128
#define DFFN    3072
#define ROWS    (BATCH*SEQ)   // 8192

__device__ __forceinline__ float gelu_f(float x) {
    return 0.5f * x * (1.0f + erff(x * 0.70710678118654752f));
}

// ---------------- block reduction (256 threads, wave64) ----------------
__device__ __forceinline__ float2 blockReduce2(float a, float b) {
    #pragma unroll
    for (int o = 32; o > 0; o >>= 1) {
        a += __shfl_down(a, o, 64);
        b += __shfl_down(b, o, 64);
    }
    __shared__ float sa[4], sb[4];
    int w = threadIdx.x >> 6, lane = threadIdx.x & 63;
    if (lane == 0) { sa[w] = a; sb[w] = b; }
    __syncthreads();
    if (threadIdx.x == 0) {
        int nw = blockDim.x >> 6;
        for (int i = 1; i < nw; ++i) { a += sa[i]; b += sb[i]; }
        sa[0] = a; sb[0] = b;
    }
    __syncthreads();
    return make_float2(sa[0], sb[0]);
}

// ---------------- LayerNorm (optionally with residual add) ----------------
__global__ __launch_bounds__(256) void ln_kernel(
    const float* __restrict__ x, const float* __restrict__ res,
    const float* __restrict__ w, const float* __restrict__ b,
    float* __restrict__ out)
{
    int r = blockIdx.x;
    const float* xr = x + (size_t)r * DMODEL;
    float v[3]; float s = 0.f, ss = 0.f;
    #pragma unroll
    for (int i = 0; i < 3; ++i) {
        int c = threadIdx.x + i * 256;
        float t = xr[c];
        if (res) t += res[(size_t)r * DMODEL + c];
        v[i] = t; s += t; ss += t * t;
    }
    float2 red = blockReduce2(s, ss);
    float mean = red.x * (1.0f / DMODEL);
    float var  = red.y * (1.0f / DMODEL) - mean * mean;
    float inv  = rsqrtf(var + 1e-5f);
    #pragma unroll
    for (int i = 0; i < 3; ++i) {
        int c = threadIdx.x + i * 256;
        out[(size_t)r * DMODEL + c] = (v[i] - mean) * inv * w[c] + b[c];
    }
}

// ---------------- SGEMM: C[M,N] = A[M,K] @ B[K,N] (+bias, +gelu) ----------
// 128x128 tile, BK=16, 256 threads, 8x8 micro-tile per thread.
// lda: row stride of A (>= K). revA: read A rows seq-flipped per batch;
// revC: write C rows seq-flipped.
__global__ __launch_bounds__(256) void sgemm(
    const float* __restrict__ A, const float* __restrict__ B,
    float* __restrict__ C, const float* __restrict__ bias,
    int M, int N, int K, int lda, int ldc, int coloff,
    int revA, int revC, int act)
{
    __shared__ float As[16][132];
    __shared__ float Bs[16][132];
    const int tid = threadIdx.x;
    const int tx = tid & 15, ty = tid >> 4;
    const int m0 = blockIdx.y * 128;
    const int n0 = blockIdx.x * 128;
    const bool fullN = (n0 + 128 <= N);

    const int arow = tid >> 2;          // 0..63
    const int acg  = (tid & 3) << 2;    // k-subcol group 0,4,8,12
    const int brow = tid >> 5;          // 0..7
    const int bcg  = (tid & 31) << 2;   // n-subcol 0..124

    int ar0 = m0 + arow, ar1 = m0 + arow + 64;
    if (revA) {
        ar0 = (ar0 & ~(SEQ - 1)) + (SEQ - 1 - (ar0 & (SEQ - 1)));
        ar1 = (ar1 & ~(SEQ - 1)) + (SEQ - 1 - (ar1 & (SEQ - 1)));
    }
    const float* Ap0 = A + (size_t)ar0 * lda + acg;
    const float* Ap1 = A + (size_t)ar1 * lda + acg;
    const float* Bp0 = B + (size_t)brow * N + n0 + bcg;
    const float* Bp1 = B + (size_t)(brow + 8) * N + n0 + bcg;

    float acc[8][8] = {};
    float4 pa0, pa1, pb0, pb1;

    auto gload = [&](int k0) {
        pa0 = *(const float4*)(Ap0 + k0);
        pa1 = *(const float4*)(Ap1 + k0);
        const float* p0 = Bp0 + (size_t)k0 * N;
        const float* p1 = Bp1 + (size_t)k0 * N;
        if (fullN) {
            pb0 = *(const float4*)p0;
            pb1 = *(const float4*)p1;
        } else {
            int c = n0 + bcg;
            pb0.x = (c + 0 < N) ? p0[0] : 0.f;
            pb0.y = (c + 1 < N) ? p0[1] : 0.f;
            pb0.z = (c + 2 < N) ? p0[2] : 0.f;
            pb0.w = (c + 3 < N) ? p0[3] : 0.f;
            pb1.x = (c + 0 < N) ? p1[0] : 0.f;
            pb1.y = (c + 1 < N) ? p1[1] : 0.f;
            pb1.z = (c + 2 < N) ? p1[2] : 0.f;
            pb1.w = (c + 3 < N) ? p1[3] : 0.f;
        }
    };

    const int ktiles = K >> 4;
    gload(0);
    for (int kt = 0; kt < ktiles; ++kt) {
        __syncthreads();
        As[acg + 0][arow] = pa0.x; As[acg + 1][arow] = pa0.y;
        As[acg + 2][arow] = pa0.z; As[acg + 3][arow] = pa0.w;
        As[acg + 0][arow + 64] = pa1.x; As[acg + 1][arow + 64] = pa1.y;
        As[acg + 2][arow + 64] = pa1.z; As[acg + 3][arow + 64] = pa1.w;
        *(float4*)&Bs[brow][bcg]     = pb0;
        *(float4*)&Bs[brow + 8][bcg] = pb1;
        __syncthreads();
        if (kt + 1 < ktiles) gload((kt + 1) << 4);
        #pragma unroll
        for (int k = 0; k < 16; ++k) {
            float a[8], b[8];
            *(float4*)(a)     = *(const float4*)&As[k][ty * 4];
            *(float4*)(a + 4) = *(const float4*)&As[k][ty * 4 + 64];
            *(float4*)(b)     = *(const float4*)&Bs[k][tx * 4];
            *(float4*)(b + 4) = *(const float4*)&Bs[k][tx * 4 + 64];
            #pragma unroll
            for (int i = 0; i < 8; ++i)
                #pragma unroll
                for (int j = 0; j < 8; ++j)
                    acc[i][j] += a[i] * b[j];
        }
    }

    #pragma unroll
    for (int ih = 0; ih < 2; ++ih) {
        #pragma unroll
        for (int i = 0; i < 4; ++i) {
            int m = m0 + ih * 64 + ty * 4 + i;
            int mdst = m;
            if (revC) mdst = (m & ~(SEQ - 1)) + (SEQ - 1 - (m & (SEQ - 1)));
            float* crow = C + (size_t)mdst * ldc + coloff;
            #pragma unroll
            for (int jh = 0; jh < 2; ++jh) {
                int n = n0 + jh * 64 + tx * 4;
                float r0 = acc[ih * 4 + i][jh * 4 + 0];
                float r1 = acc[ih * 4 + i][jh * 4 + 1];
                float r2 = acc[ih * 4 + i][jh * 4 + 2];
                float r3 = acc[ih * 4 + i][jh * 4 + 3];
                if (fullN) {
                    if (bias) { r0 += bias[n]; r1 += bias[n + 1];
                                r2 += bias[n + 2]; r3 += bias[n + 3]; }
                    if (act) { r0 = gelu_f(r0); r1 = gelu_f(r1);
                               r2 = gelu_f(r2); r3 = gelu_f(r3); }
                    float4 v = make_float4(r0, r1, r2, r3);
                    *(float4*)(crow + n) = v;
                } else {
                    float rr[4] = {r0, r1, r2, r3};
                    #pragma unroll
                    for (int j = 0; j < 4; ++j) {
                        int c = n + j;
                        if (c < N) {
                            float t = rr[j];
                            if (bias) t += bias[c];
                            if (act)  t = gelu_f(t);
                            crow[c] = t;
                        }
                    }
                }
            }
        }
    }
}

// ---------------- depthwise causal conv + SiLU ----------------
// reads xBC columns of zx; writes head channels to xcv, B/C to bc
__global__ __launch_bounds__(256) void conv_kernel(
    const float* __restrict__ zx, const float* __restrict__ cw,
    const float* __restrict__ cb, float* __restrict__ xcv,
    float* __restrict__ bc)
{
    int c = blockIdx.x * 256 + threadIdx.x;
    int r = blockIdx.y;
    if (c >= CONVDIM) return;
    int t = r & (SEQ - 1);
    int rb = r & ~(SEQ - 1);
    float acc = cb[c];
    #pragma unroll
    for (int k = 0; k < DCONV; ++k) {
        int tt = t - (DCONV - 1) + k;
        if (tt >= 0)
            acc += cw[c * DCONV + k] * zx[(size_t)(rb + tt) * DINPROJ + DINNER + c];
    }
    float v = acc / (1.0f + expf(-acc));   // silu
    if (c < DINNER) xcv[(size_t)r * DINNER + c] = v;
    else            bc[(size_t)r * 32 + (c - DINNER)] = v;
}

// ---------------- dt = softplus(z + bias), dA = exp(dt * -exp(A_log)) -----
__global__ __launch_bounds__(256) void dt_kernel(
    const float* __restrict__ zx, const float* __restrict__ dt_bias,
    const float* __restrict__ A_log, float* __restrict__ dtda)
{
    int i = blockIdx.x * 256 + threadIdx.x;
    if (i >= ROWS * NHEADS) return;
    int r = i / NHEADS, h = i - r * NHEADS;
    float v = zx[(size_t)r * DINPROJ + (DINPROJ - NHEADS) + h] + dt_bias[h];
    float dt = (v > 20.f) ? v : log1pf(expf(v));
    float A = -expf(A_log[h]);
    dtda[(size_t)r * 48 + h] = dt;
    dtda[(size_t)r * 48 + 24 + h] = expf(dt * A);
}

// ---------------- sequential selective scan: one wave per (batch, head) ---
// writes y + D*x into the (dead) xBC columns of zx: cols [1536, 3072)
__global__ __launch_bounds__(64) void scan_kernel(
    const float* __restrict__ xcv, const float* __restrict__ bc,
    const float* __restrict__ dtda, const float* __restrict__ Dp,
    float* __restrict__ yout)
{
    int bh = blockIdx.x;            // 0..95
    int b = bh / NHEADS, h = bh - b * NHEADS;
    int p = threadIdx.x;            // 0..63
    float hs[DSTATE] = {};
    float Dv = Dp[h];
    for (int t = 0; t < SEQ; ++t) {
        size_t r = (size_t)b * SEQ + t;
        float dt = dtda[r * 48 + h];
        float dA = dtda[r * 48 + 24 + h];
        float x  = xcv[r * DINNER + h * HEADDIM + p];
        float coef = dt * x;
        const float* bcr = bc + r * 32;
        float y = 0.f;
        #pragma unroll
        for (int n = 0; n < DSTATE; ++n) {
            hs[n] = hs[n] * dA + coef * bcr[n];
            y += hs[n] * bcr[16 + n];
        }
        yout[r * DINPROJ + DINNER + h * HEADDIM + p] = y + Dv * x;
    }
}

// ---------------- gated RMSNorm (IN-PLACE): z-cols of zx <- rmsnorm(y*silu(z))*w
// reads z = zx[r, 0:1536], y = zx[r, 1536:3072], writes result over z cols.
// Safe: all reads complete before blockReduce2's final barrier; rows private.
__global__ __launch_bounds__(256) void gnorm_kernel(
    float* __restrict__ zx, const float* __restrict__ nw)
{
    int r = blockIdx.x;
    float* zr = zx + (size_t)r * DINPROJ;
    float v[6]; float ss = 0.f;
    #pragma unroll
    for (int i = 0; i < 6; ++i) {
        int c = threadIdx.x + i * 256;
        float z = zr[c];
        float y = zr[DINNER + c];
        float t = y * z / (1.0f + expf(-z));
        v[i] = t; ss += t * t;
    }
    float2 red = blockReduce2(ss, 0.f);
    float sc = rsqrtf(red.x * (1.0f / DINNER) + 1e-5f);
    #pragma unroll
    for (int i = 0; i < 6; ++i) {
        int c = threadIdx.x + i * 256;
        zr[c] = v[i] * sc * nw[c];
    }
}

extern "C" void kernel_launch(void* const* d_in, const int* in_sizes, int n_in,
                              void* d_out, int out_size, void* d_ws, size_t ws_size,
                              hipStream_t stream)
{
    (void)in_sizes; (void)n_in; (void)out_size; (void)ws_size;
    const float* x     = (const float*)d_in[0];
    const float* ln1w  = (const float*)d_in[1];
    const float* ln1b  = (const float*)d_in[2];
    const float* ln2w  = (const float*)d_in[3];
    const float* ln2b  = (const float*)d_in[4];
    const float* ffnw1 = (const float*)d_in[5];
    const float* ffnb1 = (const float*)d_in[6];
    const float* ffnw2 = (const float*)d_in[7];
    const float* ffnb2 = (const float*)d_in[8];
    // per direction: in_w, conv_w, conv_b, dt_bias, A_log, D, norm_w, out_w
    const float* p[2][8];
    for (int d = 0; d < 2; ++d)
        for (int i = 0; i < 8; ++i)
            p[d][i] = (const float*)d_in[9 + d * 8 + i];

    // Workspace layout (total ~206 MB):
    //   zx   : 8192*3128 floats (102.5 MB)  — in_proj out; scan y into cols
    //          [1536,3072); gnorm in-place into cols [0,1536); FFN hmid aliases
    //   bi   : 8192*1536 (50.3 MB)          — bidirectional concat (fo|bo)
    //   xcv  : 8192*1536 (50.3 MB)          — conv head-channel output; ffo aliases
    //   bcb  : 8192*32   (1.0 MB)
    //   dtda : 8192*48   (1.5 MB)
    // xn (LN1 output) lives in d_out (fully rewritten by final LN).
    float* ws   = (float*)d_ws;
    float* zx   = ws;
    float* bi   = zx  + (size_t)ROWS * DINPROJ;
    float* xcv  = bi  + (size_t)ROWS * DINNER;
    float* bcb  = xcv + (size_t)ROWS * DINNER;
    float* dtda = bcb + (size_t)ROWS * 32;
    float* xn   = (float*)d_out;
    float* hmid = zx;    // alias: zx dead after direction loop
    float* ffo  = xcv;   // alias: xcv dead after direction loop

    // 1. ln1: x -> xn (in d_out)
    ln_kernel<<<ROWS, 256, 0, stream>>>(x, nullptr, ln1w, ln1b, xn);

    for (int d = 0; d < 2; ++d) {
        // 2. in_proj: zx = xn(rows flipped if d==1) @ in_w   [8192 x 3128]
        dim3 g1((DINPROJ + 127) / 128, ROWS / 128);
        sgemm<<<g1, 256, 0, stream>>>(xn, p[d][0], zx, nullptr,
            ROWS, DINPROJ, DMODEL, DMODEL, DINPROJ, 0, d, 0, 0);
        // 3. conv + silu -> xcv (head channels), bcb (B,C)
        conv_kernel<<<dim3(7, ROWS), 256, 0, stream>>>(zx, p[d][1], p[d][2], xcv, bcb);
        // 4. dt/dA
        dt_kernel<<<(ROWS * NHEADS + 255) / 256, 256, 0, stream>>>(
            zx, p[d][3], p[d][4], dtda);
        // 5. sequential scan -> y (+D*x) into zx cols [1536,3072)
        scan_kernel<<<BATCH * NHEADS, 64, 0, stream>>>(xcv, bcb, dtda, p[d][5], zx);
        // 6. gated RMSNorm in-place into zx cols [0,1536)
        gnorm_kernel<<<ROWS, 256, 0, stream>>>(zx, p[d][6]);
        // 7. out_proj: bi[:, d*768:(d+1)*768] = zx[:, 0:1536] @ out_w
        //    rows flipped on store if d==1
        dim3 g2(DMODEL / 128, ROWS / 128);
        sgemm<<<g2, 256, 0, stream>>>(zx, p[d][7], bi, nullptr,
            ROWS, DMODEL, DINNER, DINPROJ, DINNER, d * DMODEL, 0, d, 0);
    }

    // 8. ffn1: hmid = gelu(bi @ w1 + b1)   [8192 x 3072]  (hmid aliases zx)
    sgemm<<<dim3(DFFN / 128, ROWS / 128), 256, 0, stream>>>(
        bi, ffnw1, hmid, ffnb1, ROWS, DFFN, DINNER, DINNER, DFFN, 0, 0, 0, 1);
    // 9. ffn2: ffo = gelu(hmid @ w2 + b2)  [8192 x 768]   (ffo aliases xcv)
    sgemm<<<dim3(DMODEL / 128, ROWS / 128), 256, 0, stream>>>(
        hmid, ffnw2, ffo, ffnb2, ROWS, DMODEL, DFFN, DFFN, DMODEL, 0, 0, 0, 1);
    // 10. final layernorm(x + ffo) -> out
    ln_kernel<<<ROWS, 256, 0, stream>>>(x, ffo, ln2w, ln2b, (float*)d_out);
}

// Round 4
// 2999.726 us; speedup vs baseline: 1.7182x; 1.7182x over previous
//
#include <hip/hip_runtime.h>
#include <math.h>

#define BATCH   4
#define SEQ     2048
#define DMODEL  768
#define DSTATE  16
#define DCONV   4
#define HEADDIM 64
#define DINNER  1536
#define NHEADS  24
#define CONVDIM 1568
#define DINPROJ 3128
#define DFFN    3072
#define ROWS    (BATCH*SEQ)   // 8192

typedef __attribute__((ext_vector_type(8))) short bhalf8;   // 8 bf16 (4 VGPRs)
typedef __attribute__((ext_vector_type(4))) float floatx4;  // 4 fp32 acc

__device__ __forceinline__ float gelu_f(float x) {
    return 0.5f * x * (1.0f + erff(x * 0.70710678118654752f));
}

// truncation split: v ~= hi + lo (bf16 each), error ~2^-16 rel
__device__ __forceinline__ void splitT(float v, unsigned short& h, unsigned short& l) {
    unsigned u = __float_as_uint(v);
    h = (unsigned short)(u >> 16);
    float rem = v - __uint_as_float(u & 0xFFFF0000u);
    l = (unsigned short)(__float_as_uint(rem) >> 16);
}

// ---------------- block reduction (256 threads, wave64) ----------------
__device__ __forceinline__ float2 blockReduce2(float a, float b) {
    #pragma unroll
    for (int o = 32; o > 0; o >>= 1) {
        a += __shfl_down(a, o, 64);
        b += __shfl_down(b, o, 64);
    }
    __shared__ float sa[4], sb[4];
    int w = threadIdx.x >> 6, lane = threadIdx.x & 63;
    if (lane == 0) { sa[w] = a; sb[w] = b; }
    __syncthreads();
    if (threadIdx.x == 0) {
        int nw = blockDim.x >> 6;
        for (int i = 1; i < nw; ++i) { a += sa[i]; b += sb[i]; }
        sa[0] = a; sb[0] = b;
    }
    __syncthreads();
    return make_float2(sa[0], sb[0]);
}

// ---------------- LayerNorm (optionally with residual add) ----------------
__global__ __launch_bounds__(256) void ln_kernel(
    const float* __restrict__ x, const float* __restrict__ res,
    const float* __restrict__ w, const float* __restrict__ b,
    float* __restrict__ out)
{
    int r = blockIdx.x;
    const float* xr = x + (size_t)r * DMODEL;
    float v[3]; float s = 0.f, ss = 0.f;
    #pragma unroll
    for (int i = 0; i < 3; ++i) {
        int c = threadIdx.x + i * 256;
        float t = xr[c];
        if (res) t += res[(size_t)r * DMODEL + c];
        v[i] = t; s += t; ss += t * t;
    }
    float2 red = blockReduce2(s, ss);
    float mean = red.x * (1.0f / DMODEL);
    float var  = red.y * (1.0f / DMODEL) - mean * mean;
    float inv  = rsqrtf(var + 1e-5f);
    #pragma unroll
    for (int i = 0; i < 3; ++i) {
        int c = threadIdx.x + i * 256;
        out[(size_t)r * DMODEL + c] = (v[i] - mean) * inv * w[c] + b[c];
    }
}

// ---------------- weight transpose + bf16 hi/lo split ---------------------
// in : W[K][N] fp32 ; out: TH[N][K], TL[N][K] bf16 (RNE hi, RNE lo)
__global__ __launch_bounds__(256) void wconv(
    const float* __restrict__ W, unsigned short* __restrict__ TH,
    unsigned short* __restrict__ TL, int K, int N)
{
    __shared__ float t[32][33];
    int tx = threadIdx.x & 31, ty = threadIdx.x >> 5;  // ty 0..7
    int kb = blockIdx.y * 32, nb = blockIdx.x * 32;
    #pragma unroll
    for (int i = 0; i < 4; ++i) {
        int k = kb + ty + i * 8, n = nb + tx;
        t[ty + i * 8][tx] = (k < K && n < N) ? W[(size_t)k * N + n] : 0.f;
    }
    __syncthreads();
    #pragma unroll
    for (int i = 0; i < 4; ++i) {
        int n = nb + ty + i * 8, k = kb + tx;
        if (n < N && k < K) {
            float v = t[tx][ty + i * 8];
            unsigned u = __float_as_uint(v);
            unsigned rr = u + 0x7FFFu + ((u >> 16) & 1u);
            unsigned short hi = (unsigned short)(rr >> 16);
            float rem = v - __uint_as_float(((unsigned)hi) << 16);
            unsigned u2 = __float_as_uint(rem);
            unsigned r2 = u2 + 0x7FFFu + ((u2 >> 16) & 1u);
            unsigned short lo = (unsigned short)(r2 >> 16);
            TH[(size_t)n * K + k] = hi;
            TL[(size_t)n * K + k] = lo;
        }
    }
}

// ---------------- bf16x3 split-GEMM via MFMA ------------------------------
// C[M,N] = A[M,K] @ B[K,N] (+bias, +gelu), fp32 in/out, ~fp32 precision.
// A: fp32 [M][lda], split hi/lo on the fly during LDS staging.
// B: pre-split/transposed bf16 BH/BL with layout [N][K].
// 128x128 tile, BK=32, 4 waves (2x2), 16x16x32 bf16 MFMA, 4x4 tiles/wave.
// 3 MFMA per tile-pair: hi*hi + hi*lo + lo*hi (fp32 accumulate).
__global__ __launch_bounds__(256) void gemm3(
    const float* __restrict__ Ag,
    const unsigned short* __restrict__ BHg, const unsigned short* __restrict__ BLg,
    float* __restrict__ C, const float* __restrict__ bias,
    int M, int N, int K, int lda, int ldc, int coloff,
    int revA, int revC, int act)
{
    // padded stride 40 bf16 = 80 B: 16B-aligned rows, 2-way-banked frag reads
    __shared__ unsigned short AsH[128 * 40], AsL[128 * 40];
    __shared__ unsigned short BsH[128 * 40], BsL[128 * 40];

    const int tid = threadIdx.x;
    const int m0 = blockIdx.y * 128;
    const int n0 = blockIdx.x * 128;

    // staging assignment: row r = tid>>1 (0..127), k-halves sg = 0 or 16
    const int r  = tid >> 1;
    const int sg = (tid & 1) * 16;
    int arow = m0 + r;
    if (revA) arow = (arow & ~(SEQ - 1)) + (SEQ - 1 - (arow & (SEQ - 1)));
    const size_t abase = (size_t)arow * lda;
    const int brow = n0 + r;
    const bool bok = brow < N;
    const size_t bbase = (size_t)brow * K;

    float4 fa[4];
    bhalf8 rb0, rb1, rb2, rb3;
    const bhalf8 bz = {0, 0, 0, 0, 0, 0, 0, 0};

    auto gload = [&](int k0) {
        size_t ao = abase + k0 + sg;
        #pragma unroll
        for (int q = 0; q < 4; ++q) fa[q] = *(const float4*)(Ag + ao + 4 * q);
        if (bok) {
            size_t bo = bbase + k0 + sg;
            rb0 = *(const bhalf8*)(BHg + bo);
            rb1 = *(const bhalf8*)(BHg + bo + 8);
            rb2 = *(const bhalf8*)(BLg + bo);
            rb3 = *(const bhalf8*)(BLg + bo + 8);
        } else { rb0 = bz; rb1 = bz; rb2 = bz; rb3 = bz; }
    };

    auto stage = [&]() {
        const float* fs = (const float*)fa;
        bhalf8 h0, h1, l0, l1;
        #pragma unroll
        for (int e = 0; e < 8; ++e) {
            unsigned short h, l;
            splitT(fs[e], h, l);     h0[e] = (short)h; l0[e] = (short)l;
            splitT(fs[8 + e], h, l); h1[e] = (short)h; l1[e] = (short)l;
        }
        *(bhalf8*)&AsH[r * 40 + sg]     = h0;
        *(bhalf8*)&AsH[r * 40 + sg + 8] = h1;
        *(bhalf8*)&AsL[r * 40 + sg]     = l0;
        *(bhalf8*)&AsL[r * 40 + sg + 8] = l1;
        *(bhalf8*)&BsH[r * 40 + sg]     = rb0;
        *(bhalf8*)&BsH[r * 40 + sg + 8] = rb1;
        *(bhalf8*)&BsL[r * 40 + sg]     = rb2;
        *(bhalf8*)&BsL[r * 40 + sg + 8] = rb3;
    };

    // wave layout: 2x2, each wave owns a 64x64 quadrant
    const int w = tid >> 6, lane = tid & 63;
    const int rw = (w >> 1) * 64, cw = (w & 1) * 64;
    const int lr = lane & 15;   // m/n within 16-tile
    const int lq = lane >> 4;   // quad -> k group (frags), row group (C)

    floatx4 acc[4][4];
    const floatx4 fz = {0.f, 0.f, 0.f, 0.f};
    #pragma unroll
    for (int i = 0; i < 4; ++i)
        #pragma unroll
        for (int j = 0; j < 4; ++j) acc[i][j] = fz;

    const int ktiles = K >> 5;   // K % 32 == 0 for all our GEMMs
    gload(0);
    for (int kt = 0; kt < ktiles; ++kt) {
        __syncthreads();
        stage();
        __syncthreads();
        if (kt + 1 < ktiles) gload((kt + 1) * 32);

        bhalf8 ah[4], al[4], bh[4], bl[4];
        #pragma unroll
        for (int i = 0; i < 4; ++i) {
            ah[i] = *(const bhalf8*)&AsH[(rw + i * 16 + lr) * 40 + lq * 8];
            al[i] = *(const bhalf8*)&AsL[(rw + i * 16 + lr) * 40 + lq * 8];
            bh[i] = *(const bhalf8*)&BsH[(cw + i * 16 + lr) * 40 + lq * 8];
            bl[i] = *(const bhalf8*)&BsL[(cw + i * 16 + lr) * 40 + lq * 8];
        }
        #pragma unroll
        for (int i = 0; i < 4; ++i)
            #pragma unroll
            for (int j = 0; j < 4; ++j) {
                acc[i][j] = __builtin_amdgcn_mfma_f32_16x16x32_bf16(ah[i], bh[j], acc[i][j], 0, 0, 0);
                acc[i][j] = __builtin_amdgcn_mfma_f32_16x16x32_bf16(ah[i], bl[j], acc[i][j], 0, 0, 0);
                acc[i][j] = __builtin_amdgcn_mfma_f32_16x16x32_bf16(al[i], bh[j], acc[i][j], 0, 0, 0);
            }
    }

    // epilogue: C/D layout col=lane&15, row=quad*4+reg
    #pragma unroll
    for (int i = 0; i < 4; ++i) {
        #pragma unroll
        for (int j = 0; j < 4; ++j) {
            int gc = n0 + cw + j * 16 + lr;
            if (gc < N) {
                float bv = bias ? bias[gc] : 0.f;
                #pragma unroll
                for (int rg = 0; rg < 4; ++rg) {
                    int gm = m0 + rw + i * 16 + lq * 4 + rg;
                    if (revC) gm = (gm & ~(SEQ - 1)) + (SEQ - 1 - (gm & (SEQ - 1)));
                    float v = acc[i][j][rg] + bv;
                    if (act) v = gelu_f(v);
                    C[(size_t)gm * ldc + coloff + gc] = v;
                }
            }
        }
    }
}

// ---------------- depthwise causal conv + SiLU ----------------
__global__ __launch_bounds__(256) void conv_kernel(
    const float* __restrict__ zx, const float* __restrict__ cw,
    const float* __restrict__ cb, float* __restrict__ xcv,
    float* __restrict__ bc)
{
    int c = blockIdx.x * 256 + threadIdx.x;
    int r = blockIdx.y;
    if (c >= CONVDIM) return;
    int t = r & (SEQ - 1);
    int rb = r & ~(SEQ - 1);
    float acc = cb[c];
    #pragma unroll
    for (int k = 0; k < DCONV; ++k) {
        int tt = t - (DCONV - 1) + k;
        if (tt >= 0)
            acc += cw[c * DCONV + k] * zx[(size_t)(rb + tt) * DINPROJ + DINNER + c];
    }
    float v = acc / (1.0f + expf(-acc));   // silu
    if (c < DINNER) xcv[(size_t)r * DINNER + c] = v;
    else            bc[(size_t)r * 32 + (c - DINNER)] = v;
}

// ---------------- dt = softplus(z + bias), dA = exp(dt * -exp(A_log)) -----
__global__ __launch_bounds__(256) void dt_kernel(
    const float* __restrict__ zx, const float* __restrict__ dt_bias,
    const float* __restrict__ A_log, float* __restrict__ dtda)
{
    int i = blockIdx.x * 256 + threadIdx.x;
    if (i >= ROWS * NHEADS) return;
    int r = i / NHEADS, h = i - r * NHEADS;
    float v = zx[(size_t)r * DINPROJ + (DINPROJ - NHEADS) + h] + dt_bias[h];
    float dt = (v > 20.f) ? v : log1pf(expf(v));
    float A = -expf(A_log[h]);
    dtda[(size_t)r * 48 + h] = dt;
    dtda[(size_t)r * 48 + 24 + h] = expf(dt * A);
}

// ---------------- sequential selective scan: one wave per (batch, head) ---
__global__ __launch_bounds__(64) void scan_kernel(
    const float* __restrict__ xcv, const float* __restrict__ bc,
    const float* __restrict__ dtda, const float* __restrict__ Dp,
    float* __restrict__ yout)
{
    int bh = blockIdx.x;            // 0..95
    int b = bh / NHEADS, h = bh - b * NHEADS;
    int p = threadIdx.x;            // 0..63
    float hs[DSTATE] = {};
    float Dv = Dp[h];
    for (int t = 0; t < SEQ; ++t) {
        size_t r = (size_t)b * SEQ + t;
        float dt = dtda[r * 48 + h];
        float dA = dtda[r * 48 + 24 + h];
        float x  = xcv[r * DINNER + h * HEADDIM + p];
        float coef = dt * x;
        const float* bcr = bc + r * 32;
        float y = 0.f;
        #pragma unroll
        for (int n = 0; n < DSTATE; ++n) {
            hs[n] = hs[n] * dA + coef * bcr[n];
            y += hs[n] * bcr[16 + n];
        }
        yout[r * DINPROJ + DINNER + h * HEADDIM + p] = y + Dv * x;
    }
}

// ---------------- gated RMSNorm: out = rmsnorm(y * silu(z)) * w -----------
__global__ __launch_bounds__(256) void gnorm_kernel(
    const float* __restrict__ zx, const float* __restrict__ nw,
    float* __restrict__ out)
{
    int r = blockIdx.x;
    const float* zr = zx + (size_t)r * DINPROJ;
    float v[6]; float ss = 0.f;
    #pragma unroll
    for (int i = 0; i < 6; ++i) {
        int c = threadIdx.x + i * 256;
        float z = zr[c];
        float y = zr[DINNER + c];
        float t = y * z / (1.0f + expf(-z));
        v[i] = t; ss += t * t;
    }
    float2 red = blockReduce2(ss, 0.f);
    float sc = rsqrtf(red.x * (1.0f / DINNER) + 1e-5f);
    #pragma unroll
    for (int i = 0; i < 6; ++i) {
        int c = threadIdx.x + i * 256;
        out[(size_t)r * DINNER + c] = v[i] * sc * nw[c];
    }
}

extern "C" void kernel_launch(void* const* d_in, const int* in_sizes, int n_in,
                              void* d_out, int out_size, void* d_ws, size_t ws_size,
                              hipStream_t stream)
{
    (void)in_sizes; (void)n_in; (void)out_size; (void)ws_size;
    const float* x     = (const float*)d_in[0];
    const float* ln1w  = (const float*)d_in[1];
    const float* ln1b  = (const float*)d_in[2];
    const float* ln2w  = (const float*)d_in[3];
    const float* ln2b  = (const float*)d_in[4];
    const float* ffnw1 = (const float*)d_in[5];
    const float* ffnb1 = (const float*)d_in[6];
    const float* ffnw2 = (const float*)d_in[7];
    const float* ffnb2 = (const float*)d_in[8];
    // per direction: in_w, conv_w, conv_b, dt_bias, A_log, D, norm_w, out_w
    const float* p[2][8];
    for (int d = 0; d < 2; ++d)
        for (int i = 0; i < 8; ++i)
            p[d][i] = (const float*)d_in[9 + d * 8 + i];

    // Workspace (~215 MB):
    //   zx   : 8192*3128 fp32 (102.5 MB) — in_proj out; scan y into cols
    //          [1536,3072); hmid (8192*3072 fp32) aliases after dir loop
    //   bi   : 8192*1536 fp32 (50.3 MB)  — bidir concat (fo|bo)
    //   S    : 8192*1536 fp32 (50.3 MB)  — xcv -> zn -> ffn wts + ffo
    //   Wbuf : 2*2402304 ushort (9.6 MB) — direction weights hi/lo (transposed)
    //   bcb / dtda : small
    // LN1 output (xn) lives in d_out (fully rewritten by final LN).
    float* ws   = (float*)d_ws;
    float* zx   = ws;
    float* bi   = zx + (size_t)ROWS * DINPROJ;
    float* S    = bi + (size_t)ROWS * DINNER;
    float* Wbuf = S  + (size_t)ROWS * DINNER;
    float* bcb  = Wbuf + 2402304;
    float* dtda = bcb + (size_t)ROWS * 32;
    float* xn   = (float*)d_out;
    float* xcv  = S;
    float* zn   = S;
    float* hmid = zx;
    float* ffo  = S + 4718592;   // after ffn1-weight region (18.9 MB)

    // 1. ln1: x -> xn (in d_out)
    ln_kernel<<<ROWS, 256, 0, stream>>>(x, nullptr, ln1w, ln1b, xn);

    for (int d = 0; d < 2; ++d) {
        unsigned short* WH = (unsigned short*)Wbuf;
        // in_proj weights: [768][3128] -> T [3128][768] hi/lo
        unsigned short* WL = WH + (size_t)DINPROJ * DMODEL;
        wconv<<<dim3((DINPROJ + 31) / 32, DMODEL / 32), 256, 0, stream>>>(
            p[d][0], WH, WL, DMODEL, DINPROJ);
        // 2. in_proj: zx = xn(flip if d==1) @ in_w   [8192 x 3128]
        gemm3<<<dim3((DINPROJ + 127) / 128, ROWS / 128), 256, 0, stream>>>(
            xn, WH, WL, zx, nullptr,
            ROWS, DINPROJ, DMODEL, DMODEL, DINPROJ, 0, d, 0, 0);
        // 3. conv + silu -> xcv (head channels), bcb (B,C)
        conv_kernel<<<dim3(7, ROWS), 256, 0, stream>>>(zx, p[d][1], p[d][2], xcv, bcb);
        // 4. dt/dA
        dt_kernel<<<(ROWS * NHEADS + 255) / 256, 256, 0, stream>>>(
            zx, p[d][3], p[d][4], dtda);
        // 5. sequential scan -> y (+D*x) into zx cols [1536,3072)
        scan_kernel<<<BATCH * NHEADS, 64, 0, stream>>>(xcv, bcb, dtda, p[d][5], zx);
        // 6. gated RMSNorm -> zn (xcv dead)
        gnorm_kernel<<<ROWS, 256, 0, stream>>>(zx, p[d][6], zn);
        // 7. out_proj: bi[:, d*768:(d+1)*768] = zn @ out_w, flip store if d==1
        unsigned short* WL2 = WH + (size_t)DMODEL * DINNER;
        wconv<<<dim3(DMODEL / 32, DINNER / 32), 256, 0, stream>>>(
            p[d][7], WH, WL2, DINNER, DMODEL);
        gemm3<<<dim3(DMODEL / 128, ROWS / 128), 256, 0, stream>>>(
            zn, WH, WL2, bi, nullptr,
            ROWS, DMODEL, DINNER, DINNER, DINNER, d * DMODEL, 0, d, 0);
    }

    // 8. ffn1: hmid = gelu(bi @ w1 + b1)  [8192 x 3072]; weights in S (zn dead)
    {
        unsigned short* WH = (unsigned short*)S;
        unsigned short* WL = WH + (size_t)DFFN * DINNER;
        wconv<<<dim3(DFFN / 32, DINNER / 32), 256, 0, stream>>>(
            ffnw1, WH, WL, DINNER, DFFN);
        gemm3<<<dim3(DFFN / 128, ROWS / 128), 256, 0, stream>>>(
            bi, WH, WL, hmid, ffnb1,
            ROWS, DFFN, DINNER, DINNER, DFFN, 0, 0, 0, 1);
    }
    // 9. ffn2: ffo = gelu(hmid @ w2 + b2) [8192 x 768]; weights in S (ffn1 wts dead)
    {
        unsigned short* WH = (unsigned short*)S;
        unsigned short* WL = WH + (size_t)DMODEL * DFFN;
        wconv<<<dim3(DMODEL / 32, DFFN / 32), 256, 0, stream>>>(
            ffnw2, WH, WL, DFFN, DMODEL);
        gemm3<<<dim3(DMODEL / 128, ROWS / 128), 256, 0, stream>>>(
            hmid, WH, WL, ffo, ffnb2,
            ROWS, DMODEL, DFFN, DFFN, DMODEL, 0, 0, 0, 1);
    }
    // 10. final layernorm(x + ffo) -> out
    ln_kernel<<<ROWS, 256, 0, stream>>>(x, ffo, ln2w, ln2b, (float*)d_out);
}

// Round 7
// 1560.649 us; speedup vs baseline: 3.3026x; 1.9221x over previous
//
#include <hip/hip_runtime.h>
#include <math.h>

#define BATCH   4
#define SEQ     2048
#define DMODEL  768
#define DSTATE  16
#define DCONV   4
#define HEADDIM 64
#define DINNER  1536
#define NHEADS  24
#define CONVDIM 1568
#define DINPROJ 3128
#define DFFN    3072
#define ROWS    (BATCH*SEQ)   // 8192
#define QCH     128           // scan chunk length
#define NCHUNK  (SEQ/QCH)     // 16

typedef __attribute__((ext_vector_type(8))) short bhalf8;   // 8 bf16 (4 VGPRs)
typedef __attribute__((ext_vector_type(4))) float floatx4;  // 4 fp32 acc

__device__ __forceinline__ float gelu_f(float x) {
    return 0.5f * x * (1.0f + erff(x * 0.70710678118654752f));
}

// truncation split: v ~= hi + lo (bf16 each), error ~2^-16 rel
__device__ __forceinline__ void splitT(float v, unsigned short& h, unsigned short& l) {
    unsigned u = __float_as_uint(v);
    h = (unsigned short)(u >> 16);
    float rem = v - __uint_as_float(u & 0xFFFF0000u);
    l = (unsigned short)(__float_as_uint(rem) >> 16);
}

// ---------------- block reduction (256 threads, wave64) ----------------
__device__ __forceinline__ float2 blockReduce2(float a, float b) {
    #pragma unroll
    for (int o = 32; o > 0; o >>= 1) {
        a += __shfl_down(a, o, 64);
        b += __shfl_down(b, o, 64);
    }
    __shared__ float sa[4], sb[4];
    int w = threadIdx.x >> 6, lane = threadIdx.x & 63;
    if (lane == 0) { sa[w] = a; sb[w] = b; }
    __syncthreads();
    if (threadIdx.x == 0) {
        int nw = blockDim.x >> 6;
        for (int i = 1; i < nw; ++i) { a += sa[i]; b += sb[i]; }
        sa[0] = a; sb[0] = b;
    }
    __syncthreads();
    return make_float2(sa[0], sb[0]);
}

// ---------------- LayerNorm (optionally with residual add) ----------------
__global__ __launch_bounds__(256) void ln_kernel(
    const float* __restrict__ x, const float* __restrict__ res,
    const float* __restrict__ w, const float* __restrict__ b,
    float* __restrict__ out)
{
    int r = blockIdx.x;
    const float* xr = x + (size_t)r * DMODEL;
    float v[3]; float s = 0.f, ss = 0.f;
    #pragma unroll
    for (int i = 0; i < 3; ++i) {
        int c = threadIdx.x + i * 256;
        float t = xr[c];
        if (res) t += res[(size_t)r * DMODEL + c];
        v[i] = t; s += t; ss += t * t;
    }
    float2 red = blockReduce2(s, ss);
    float mean = red.x * (1.0f / DMODEL);
    float var  = red.y * (1.0f / DMODEL) - mean * mean;
    float inv  = rsqrtf(var + 1e-5f);
    #pragma unroll
    for (int i = 0; i < 3; ++i) {
        int c = threadIdx.x + i * 256;
        out[(size_t)r * DMODEL + c] = (v[i] - mean) * inv * w[c] + b[c];
    }
}

// ---------------- weight transpose + bf16 hi/lo split ---------------------
// in : W[K][N] fp32 ; out: TH[N][K], TL[N][K] bf16 (RNE hi, RNE lo)
__global__ __launch_bounds__(256) void wconv(
    const float* __restrict__ W, unsigned short* __restrict__ TH,
    unsigned short* __restrict__ TL, int K, int N)
{
    __shared__ float t[32][33];
    int tx = threadIdx.x & 31, ty = threadIdx.x >> 5;  // ty 0..7
    int kb = blockIdx.y * 32, nb = blockIdx.x * 32;
    #pragma unroll
    for (int i = 0; i < 4; ++i) {
        int k = kb + ty + i * 8, n = nb + tx;
        t[ty + i * 8][tx] = (k < K && n < N) ? W[(size_t)k * N + n] : 0.f;
    }
    __syncthreads();
    #pragma unroll
    for (int i = 0; i < 4; ++i) {
        int n = nb + ty + i * 8, k = kb + tx;
        if (n < N && k < K) {
            float v = t[tx][ty + i * 8];
            unsigned u = __float_as_uint(v);
            unsigned rr = u + 0x7FFFu + ((u >> 16) & 1u);
            unsigned short hi = (unsigned short)(rr >> 16);
            float rem = v - __uint_as_float(((unsigned)hi) << 16);
            unsigned u2 = __float_as_uint(rem);
            unsigned r2 = u2 + 0x7FFFu + ((u2 >> 16) & 1u);
            unsigned short lo = (unsigned short)(r2 >> 16);
            TH[(size_t)n * K + k] = hi;
            TL[(size_t)n * K + k] = lo;
        }
    }
}

// ---------------- bf16x3 split-GEMM via MFMA ------------------------------
__global__ __launch_bounds__(256) void gemm3(
    const float* __restrict__ Ag,
    const unsigned short* __restrict__ BHg, const unsigned short* __restrict__ BLg,
    float* __restrict__ C, const float* __restrict__ bias,
    int M, int N, int K, int lda, int ldc, int coloff,
    int revA, int revC, int act)
{
    // padded stride 40 bf16 = 80 B: 16B-aligned rows, 2-way-banked frag reads
    __shared__ unsigned short AsH[128 * 40], AsL[128 * 40];
    __shared__ unsigned short BsH[128 * 40], BsL[128 * 40];

    const int tid = threadIdx.x;
    const int m0 = blockIdx.y * 128;
    const int n0 = blockIdx.x * 128;

    // staging assignment: row r = tid>>1 (0..127), k-halves sg = 0 or 16
    const int r  = tid >> 1;
    const int sg = (tid & 1) * 16;
    int arow = m0 + r;
    if (revA) arow = (arow & ~(SEQ - 1)) + (SEQ - 1 - (arow & (SEQ - 1)));
    const size_t abase = (size_t)arow * lda;
    const int brow = n0 + r;
    const bool bok = brow < N;
    const size_t bbase = (size_t)brow * K;

    float4 fa[4];
    bhalf8 rb0, rb1, rb2, rb3;
    const bhalf8 bz = {0, 0, 0, 0, 0, 0, 0, 0};

    auto gload = [&](int k0) {
        size_t ao = abase + k0 + sg;
        #pragma unroll
        for (int q = 0; q < 4; ++q) fa[q] = *(const float4*)(Ag + ao + 4 * q);
        if (bok) {
            size_t bo = bbase + k0 + sg;
            rb0 = *(const bhalf8*)(BHg + bo);
            rb1 = *(const bhalf8*)(BHg + bo + 8);
            rb2 = *(const bhalf8*)(BLg + bo);
            rb3 = *(const bhalf8*)(BLg + bo + 8);
        } else { rb0 = bz; rb1 = bz; rb2 = bz; rb3 = bz; }
    };

    auto stage = [&]() {
        const float* fs = (const float*)fa;
        bhalf8 h0, h1, l0, l1;
        #pragma unroll
        for (int e = 0; e < 8; ++e) {
            unsigned short h, l;
            splitT(fs[e], h, l);     h0[e] = (short)h; l0[e] = (short)l;
            splitT(fs[8 + e], h, l); h1[e] = (short)h; l1[e] = (short)l;
        }
        *(bhalf8*)&AsH[r * 40 + sg]     = h0;
        *(bhalf8*)&AsH[r * 40 + sg + 8] = h1;
        *(bhalf8*)&AsL[r * 40 + sg]     = l0;
        *(bhalf8*)&AsL[r * 40 + sg + 8] = l1;
        *(bhalf8*)&BsH[r * 40 + sg]     = rb0;
        *(bhalf8*)&BsH[r * 40 + sg + 8] = rb1;
        *(bhalf8*)&BsL[r * 40 + sg]     = rb2;
        *(bhalf8*)&BsL[r * 40 + sg + 8] = rb3;
    };

    // wave layout: 2x2, each wave owns a 64x64 quadrant
    const int w = tid >> 6, lane = tid & 63;
    const int rw = (w >> 1) * 64, cw = (w & 1) * 64;
    const int lr = lane & 15;   // m/n within 16-tile
    const int lq = lane >> 4;   // quad -> k group (frags), row group (C)

    floatx4 acc[4][4];
    const floatx4 fz = {0.f, 0.f, 0.f, 0.f};
    #pragma unroll
    for (int i = 0; i < 4; ++i)
        #pragma unroll
        for (int j = 0; j < 4; ++j) acc[i][j] = fz;

    const int ktiles = K >> 5;   // K % 32 == 0 for all our GEMMs
    gload(0);
    for (int kt = 0; kt < ktiles; ++kt) {
        __syncthreads();
        stage();
        __syncthreads();
        if (kt + 1 < ktiles) gload((kt + 1) * 32);

        bhalf8 ah[4], al[4], bh[4], bl[4];
        #pragma unroll
        for (int i = 0; i < 4; ++i) {
            ah[i] = *(const bhalf8*)&AsH[(rw + i * 16 + lr) * 40 + lq * 8];
            al[i] = *(const bhalf8*)&AsL[(rw + i * 16 + lr) * 40 + lq * 8];
            bh[i] = *(const bhalf8*)&BsH[(cw + i * 16 + lr) * 40 + lq * 8];
            bl[i] = *(const bhalf8*)&BsL[(cw + i * 16 + lr) * 40 + lq * 8];
        }
        #pragma unroll
        for (int i = 0; i < 4; ++i)
            #pragma unroll
            for (int j = 0; j < 4; ++j) {
                acc[i][j] = __builtin_amdgcn_mfma_f32_16x16x32_bf16(ah[i], bh[j], acc[i][j], 0, 0, 0);
                acc[i][j] = __builtin_amdgcn_mfma_f32_16x16x32_bf16(ah[i], bl[j], acc[i][j], 0, 0, 0);
                acc[i][j] = __builtin_amdgcn_mfma_f32_16x16x32_bf16(al[i], bh[j], acc[i][j], 0, 0, 0);
            }
    }

    // epilogue: C/D layout col=lane&15, row=quad*4+reg
    #pragma unroll
    for (int i = 0; i < 4; ++i) {
        #pragma unroll
        for (int j = 0; j < 4; ++j) {
            int gc = n0 + cw + j * 16 + lr;
            if (gc < N) {
                float bv = bias ? bias[gc] : 0.f;
                #pragma unroll
                for (int rg = 0; rg < 4; ++rg) {
                    int gm = m0 + rw + i * 16 + lq * 4 + rg;
                    if (revC) gm = (gm & ~(SEQ - 1)) + (SEQ - 1 - (gm & (SEQ - 1)));
                    float v = acc[i][j][rg] + bv;
                    if (act) v = gelu_f(v);
                    C[(size_t)gm * ldc + coloff + gc] = v;
                }
            }
        }
    }
}

// ---------------- depthwise causal conv + SiLU ----------------
__global__ __launch_bounds__(256) void conv_kernel(
    const float* __restrict__ zx, const float* __restrict__ cw,
    const float* __restrict__ cb, float* __restrict__ xcv,
    float* __restrict__ bc)
{
    int c = blockIdx.x * 256 + threadIdx.x;
    int r = blockIdx.y;
    if (c >= CONVDIM) return;
    int t = r & (SEQ - 1);
    int rb = r & ~(SEQ - 1);
    float acc = cb[c];
    #pragma unroll
    for (int k = 0; k < DCONV; ++k) {
        int tt = t - (DCONV - 1) + k;
        if (tt >= 0)
            acc += cw[c * DCONV + k] * zx[(size_t)(rb + tt) * DINPROJ + DINNER + c];
    }
    float v = acc / (1.0f + expf(-acc));   // silu
    if (c < DINNER) xcv[(size_t)r * DINNER + c] = v;
    else            bc[(size_t)r * 32 + (c - DINNER)] = v;
}

// ---------------- dt = softplus(z + bias), dA = exp(dt * -exp(A_log)) -----
__global__ __launch_bounds__(256) void dt_kernel(
    const float* __restrict__ zx, const float* __restrict__ dt_bias,
    const float* __restrict__ A_log, float* __restrict__ dtda)
{
    int i = blockIdx.x * 256 + threadIdx.x;
    if (i >= ROWS * NHEADS) return;
    int r = i / NHEADS, h = i - r * NHEADS;
    float v = zx[(size_t)r * DINPROJ + (DINPROJ - NHEADS) + h] + dt_bias[h];
    float dt = (v > 20.f) ? v : log1pf(expf(v));
    float A = -expf(A_log[h]);
    dtda[(size_t)r * 48 + h] = dt;
    dtda[(size_t)r * 48 + 24 + h] = expf(dt * A);
}

// ---------------- chunked scan, phase A: per-chunk local scan -------------
// grid: 96*NCHUNK waves. Each computes a zero-init scan over its chunk,
// writes y_local + D*x into zx cols [1536,3072), chunk-final state to S,
// and within-chunk cumulative dA prefix to cd.
__global__ __launch_bounds__(64) void scan_a(
    const float* __restrict__ xcv, const float* __restrict__ bc,
    const float* __restrict__ dtda, const float* __restrict__ Dp,
    float* __restrict__ yout, float* __restrict__ S, float* __restrict__ cd)
{
    int blk = blockIdx.x;
    int bh = blk / NCHUNK, c = blk - bh * NCHUNK;
    int b = bh / NHEADS, h = bh - b * NHEADS;
    int p = threadIdx.x;
    float hs[DSTATE] = {};
    float Dv = Dp[h];
    float cum = 1.f;
    int t0 = c * QCH;
    for (int t = t0; t < t0 + QCH; ++t) {
        size_t r = (size_t)b * SEQ + t;
        float dt = dtda[r * 48 + h];
        float dA = dtda[r * 48 + 24 + h];
        float x  = xcv[r * DINNER + h * HEADDIM + p];
        cum *= dA;
        float coef = dt * x;
        const float* bcr = bc + r * 32;
        float y = 0.f;
        #pragma unroll
        for (int n = 0; n < DSTATE; ++n) {
            hs[n] = hs[n] * dA + coef * bcr[n];
            y += hs[n] * bcr[16 + n];
        }
        yout[r * DINPROJ + DINNER + h * HEADDIM + p] = y + Dv * x;
        if (p == 0) cd[r * NHEADS + h] = cum;
    }
    float* Sp = S + (((size_t)bh * NCHUNK + c) * HEADDIM + p) * DSTATE;
    #pragma unroll
    for (int n = 0; n < DSTATE; ++n) Sp[n] = hs[n];
}

// ---------------- chunked scan, phase B: sequential chunk combine ---------
// grid: 96 waves. In-place: S[bh][c] (local final state) is overwritten with
// the carry-in state H_c for chunk c.  H_0 = 0; H_{c+1} = P_c*H_c + S_c.
__global__ __launch_bounds__(64) void scan_b(
    const float* __restrict__ cd, float* __restrict__ S)
{
    int bh = blockIdx.x;
    int b = bh / NHEADS, h = bh - b * NHEADS;
    int p = threadIdx.x;
    float H[DSTATE] = {};
    for (int c = 0; c < NCHUNK; ++c) {
        float* Sp = S + (((size_t)bh * NCHUNK + c) * HEADDIM + p) * DSTATE;
        float P = cd[((size_t)b * SEQ + c * QCH + QCH - 1) * NHEADS + h];
        float s[DSTATE];
        #pragma unroll
        for (int n = 0; n < DSTATE; ++n) s[n] = Sp[n];
        #pragma unroll
        for (int n = 0; n < DSTATE; ++n) Sp[n] = H[n];
        #pragma unroll
        for (int n = 0; n < DSTATE; ++n) H[n] = P * H[n] + s[n];
    }
}

// ---------------- chunked scan, phase C: carry correction -----------------
// grid: 96*(NCHUNK-1) waves (chunk 0 has zero carry).
// y_t += cd_t * (C_t . H_chunk)
__global__ __launch_bounds__(64) void scan_c(
    const float* __restrict__ bc, const float* __restrict__ cd,
    const float* __restrict__ S, float* __restrict__ yout)
{
    int blk = blockIdx.x;
    int bh = blk / (NCHUNK - 1), c = blk - bh * (NCHUNK - 1) + 1;
    int b = bh / NHEADS, h = bh - b * NHEADS;
    int p = threadIdx.x;
    const float* Hp = S + (((size_t)bh * NCHUNK + c) * HEADDIM + p) * DSTATE;
    float H[DSTATE];
    #pragma unroll
    for (int n = 0; n < DSTATE; ++n) H[n] = Hp[n];
    int t0 = c * QCH;
    for (int t = t0; t < t0 + QCH; ++t) {
        size_t r = (size_t)b * SEQ + t;
        const float* Cr = bc + r * 32 + 16;
        float dot = 0.f;
        #pragma unroll
        for (int n = 0; n < DSTATE; ++n) dot += H[n] * Cr[n];
        float cum = cd[r * NHEADS + h];
        yout[r * DINPROJ + DINNER + h * HEADDIM + p] += cum * dot;
    }
}

// ---------------- gated RMSNorm: out = rmsnorm(y * silu(z)) * w -----------
__global__ __launch_bounds__(256) void gnorm_kernel(
    const float* __restrict__ zx, const float* __restrict__ nw,
    float* __restrict__ out)
{
    int r = blockIdx.x;
    const float* zr = zx + (size_t)r * DINPROJ;
    float v[6]; float ss = 0.f;
    #pragma unroll
    for (int i = 0; i < 6; ++i) {
        int c = threadIdx.x + i * 256;
        float z = zr[c];
        float y = zr[DINNER + c];
        float t = y * z / (1.0f + expf(-z));
        v[i] = t; ss += t * t;
    }
    float2 red = blockReduce2(ss, 0.f);
    float sc = rsqrtf(red.x * (1.0f / DINNER) + 1e-5f);
    #pragma unroll
    for (int i = 0; i < 6; ++i) {
        int c = threadIdx.x + i * 256;
        out[(size_t)r * DINNER + c] = v[i] * sc * nw[c];
    }
}

extern "C" void kernel_launch(void* const* d_in, const int* in_sizes, int n_in,
                              void* d_out, int out_size, void* d_ws, size_t ws_size,
                              hipStream_t stream)
{
    (void)in_sizes; (void)n_in; (void)out_size; (void)ws_size;
    const float* x     = (const float*)d_in[0];
    const float* ln1w  = (const float*)d_in[1];
    const float* ln1b  = (const float*)d_in[2];
    const float* ln2w  = (const float*)d_in[3];
    const float* ln2b  = (const float*)d_in[4];
    const float* ffnw1 = (const float*)d_in[5];
    const float* ffnb1 = (const float*)d_in[6];
    const float* ffnw2 = (const float*)d_in[7];
    const float* ffnb2 = (const float*)d_in[8];
    // per direction: in_w, conv_w, conv_b, dt_bias, A_log, D, norm_w, out_w
    const float* p[2][8];
    for (int d = 0; d < 2; ++d)
        for (int i = 0; i < 8; ++i)
            p[d][i] = (const float*)d_in[9 + d * 8 + i];

    // Workspace (215.7 MB — identical layout to the round-4 PASSING run):
    //   zx   : 8192*3128 fp32 (102.5 MB) — in_proj out; scan y into cols
    //          [1536,3072); hmid aliases after dir loop
    //   bi   : 8192*1536 fp32 (50.3 MB)  — bidir concat (fo|bo)
    //   S    : 8192*1536 fp32 (50.3 MB)  — xcv -> zn -> ffn wts + ffo
    //   Wbuf : 2402304 floats (9.6 MB)   — direction weights hi/lo (transposed)
    //          ALSO aliases Sbuf (1,572,864 fl) + cdbf (196,608 fl) during the
    //          scan window: in_proj weights are dead after the in_proj GEMM,
    //          and out_proj wconv rewrites Wbuf only after scan_c/gnorm.
    //   bcb / dtda : small
    float* ws   = (float*)d_ws;
    float* zx   = ws;
    float* bi   = zx + (size_t)ROWS * DINPROJ;
    float* S    = bi + (size_t)ROWS * DINNER;
    float* Wbuf = S  + (size_t)ROWS * DINNER;
    float* bcb  = Wbuf + 2402304;
    float* dtda = bcb + (size_t)ROWS * 32;
    float* Sbuf = Wbuf;                       // alias (dead in_proj weights)
    float* cdbf = Wbuf + (size_t)BATCH * NHEADS * NCHUNK * HEADDIM * DSTATE;
    float* xn   = (float*)d_out;
    float* xcv  = S;
    float* zn   = S;
    float* hmid = zx;
    float* ffo  = S + 4718592;   // after ffn1-weight region (18.9 MB)

    // 1. ln1: x -> xn (in d_out)
    ln_kernel<<<ROWS, 256, 0, stream>>>(x, nullptr, ln1w, ln1b, xn);

    for (int d = 0; d < 2; ++d) {
        unsigned short* WH = (unsigned short*)Wbuf;
        // in_proj weights: [768][3128] -> T [3128][768] hi/lo
        unsigned short* WL = WH + (size_t)DINPROJ * DMODEL;
        wconv<<<dim3((DINPROJ + 31) / 32, DMODEL / 32), 256, 0, stream>>>(
            p[d][0], WH, WL, DMODEL, DINPROJ);
        // 2. in_proj: zx = xn(flip if d==1) @ in_w   [8192 x 3128]
        gemm3<<<dim3((DINPROJ + 127) / 128, ROWS / 128), 256, 0, stream>>>(
            xn, WH, WL, zx, nullptr,
            ROWS, DINPROJ, DMODEL, DMODEL, DINPROJ, 0, d, 0, 0);
        // 3. conv + silu -> xcv (head channels), bcb (B,C)
        conv_kernel<<<dim3(7, ROWS), 256, 0, stream>>>(zx, p[d][1], p[d][2], xcv, bcb);
        // 4. dt/dA
        dt_kernel<<<(ROWS * NHEADS + 255) / 256, 256, 0, stream>>>(
            zx, p[d][3], p[d][4], dtda);
        // 5. chunked scan -> y (+D*x) into zx cols [1536,3072)
        //    (Sbuf/cdbf live in Wbuf — in_proj weights dead from here)
        scan_a<<<BATCH * NHEADS * NCHUNK, 64, 0, stream>>>(
            xcv, bcb, dtda, p[d][5], zx, Sbuf, cdbf);
        scan_b<<<BATCH * NHEADS, 64, 0, stream>>>(cdbf, Sbuf);
        scan_c<<<BATCH * NHEADS * (NCHUNK - 1), 64, 0, stream>>>(
            bcb, cdbf, Sbuf, zx);
        // 6. gated RMSNorm -> zn (xcv dead)
        gnorm_kernel<<<ROWS, 256, 0, stream>>>(zx, p[d][6], zn);
        // 7. out_proj: bi[:, d*768:(d+1)*768] = zn @ out_w, flip store if d==1
        //    (wconv rewrites Wbuf — scan buffers dead from here)
        unsigned short* WL2 = WH + (size_t)DMODEL * DINNER;
        wconv<<<dim3(DMODEL / 32, DINNER / 32), 256, 0, stream>>>(
            p[d][7], WH, WL2, DINNER, DMODEL);
        gemm3<<<dim3(DMODEL / 128, ROWS / 128), 256, 0, stream>>>(
            zn, WH, WL2, bi, nullptr,
            ROWS, DMODEL, DINNER, DINNER, DINNER, d * DMODEL, 0, d, 0);
    }

    // 8. ffn1: hmid = gelu(bi @ w1 + b1)  [8192 x 3072]; weights in S (zn dead)
    {
        unsigned short* WH = (unsigned short*)S;
        unsigned short* WL = WH + (size_t)DFFN * DINNER;
        wconv<<<dim3(DFFN / 32, DINNER / 32), 256, 0, stream>>>(
            ffnw1, WH, WL, DINNER, DFFN);
        gemm3<<<dim3(DFFN / 128, ROWS / 128), 256, 0, stream>>>(
            bi, WH, WL, hmid, ffnb1,
            ROWS, DFFN, DINNER, DINNER, DFFN, 0, 0, 0, 1);
    }
    // 9. ffn2: ffo = gelu(hmid @ w2 + b2) [8192 x 768]; weights in S (ffn1 wts dead)
    {
        unsigned short* WH = (unsigned short*)S;
        unsigned short* WL = WH + (size_t)DMODEL * DFFN;
        wconv<<<dim3(DMODEL / 32, DFFN / 32), 256, 0, stream>>>(
            ffnw2, WH, WL, DFFN, DMODEL);
        gemm3<<<dim3(DMODEL / 128, ROWS / 128), 256, 0, stream>>>(
            hmid, WH, WL, ffo, ffnb2,
            ROWS, DMODEL, DFFN, DFFN, DMODEL, 0, 0, 0, 1);
    }
    // 10. final layernorm(x + ffo) -> out
    ln_kernel<<<ROWS, 256, 0, stream>>>(x, ffo, ln2w, ln2b, (float*)d_out);
}